// Round 1
// baseline (2151.878 us; speedup 1.0000x reference)
//
#include <hip/hip_runtime.h>

#define BB 8
#define IC 32
#define OC 64
#define HH 256
#define WW 256
#define EPS 1e-5f

// ---- workspace layout (float indices) ----
#define WS_GAP   0                     // 256 floats
#define WS_BIDX  256                   // 8 ints (4B each, aliased into float slots)
#define WS_W1T   264                   // 32*9*64 = 18432  (folded mw1, [ic][k][oc])
#define WS_B1F   (WS_W1T + 18432)      // 64
#define WS_W2T   (WS_B1F + 64)         // 64*25*64 = 102400 ([ic][k][oc])
#define WS_B2F   (WS_W2T + 102400)     // 64
#define WS_SXWT  (WS_B2F + 64)         // 32*25*64 = 51200
#define WS_SXBF  (WS_SXWT + 51200)     // 64
#define WS_SYWT  (WS_SXBF + 64)        // 51200
#define WS_SYBF  (WS_SYWT + 51200)     // 64
#define WS_LWT   (WS_SYBF + 64)        // 51200
#define WS_LBF   (WS_LWT + 51200)      // 64

// ------------------------------------------------------------------
// prep: fold BN into transposed weights + biases
// ------------------------------------------------------------------
__global__ void prep_kernel(const float* __restrict__ mw1, const float* __restrict__ mb1, const float* __restrict__ mbn1,
                            const float* __restrict__ mw2, const float* __restrict__ mb2, const float* __restrict__ mbn2,
                            const float* __restrict__ sxw, const float* __restrict__ sxb, const float* __restrict__ sxbn,
                            const float* __restrict__ syw, const float* __restrict__ syb, const float* __restrict__ sybn,
                            const float* __restrict__ lw,  const float* __restrict__ lb,  const float* __restrict__ lbn,
                            float* __restrict__ ws) {
    int idx = blockIdx.x * 256 + threadIdx.x;
    // mw1: (64,32,3,3) -> w1t[ic][k][oc], folded by s1[oc]
    if (idx < 18432) {
        int oc = idx & 63, k = (idx >> 6) % 9, ic = idx / (9 * 64);
        float s = mbn1[oc] * rsqrtf(mbn1[192 + oc] + EPS);
        ws[WS_W1T + idx] = mw1[(oc * IC + ic) * 9 + k] * s;
    }
    // mw2: (64,64,5,5) -> w2t[ic][k][oc]
    if (idx < 102400) {
        int oc = idx & 63, k = (idx >> 6) % 25, ic = idx / (25 * 64);
        float s = mbn2[oc] * rsqrtf(mbn2[192 + oc] + EPS);
        ws[WS_W2T + idx] = mw2[(oc * OC + ic) * 25 + k] * s;
    }
    // sx/sy/l: (64,32,5,5) -> [ic][k][oc]
    if (idx < 51200) {
        int oc = idx & 63, k = (idx >> 6) % 25, ic = idx / (25 * 64);
        float ssx = sxbn[oc] * rsqrtf(sxbn[192 + oc] + EPS);
        float ssy = sybn[oc] * rsqrtf(sybn[192 + oc] + EPS);
        float sl  = lbn[oc]  * rsqrtf(lbn[192 + oc]  + EPS);
        int src = (oc * IC + (idx / (25 * 64))) * 25 + k;
        (void)src;
        ws[WS_SXWT + idx] = sxw[(oc * IC + ic) * 25 + k] * ssx;
        ws[WS_SYWT + idx] = syw[(oc * IC + ic) * 25 + k] * ssy;
        ws[WS_LWT  + idx] = lw [(oc * IC + ic) * 25 + k] * sl;
    }
    if (idx < 64) {
        float s1 = mbn1[idx] * rsqrtf(mbn1[192 + idx] + EPS);
        ws[WS_B1F + idx] = (mb1[idx] - mbn1[128 + idx]) * s1 + mbn1[64 + idx];
        float s2 = mbn2[idx] * rsqrtf(mbn2[192 + idx] + EPS);
        ws[WS_B2F + idx] = (mb2[idx] - mbn2[128 + idx]) * s2 + mbn2[64 + idx];
        float sx = sxbn[idx] * rsqrtf(sxbn[192 + idx] + EPS);
        ws[WS_SXBF + idx] = (sxb[idx] - sxbn[128 + idx]) * sx + sxbn[64 + idx];
        float sy = sybn[idx] * rsqrtf(sybn[192 + idx] + EPS);
        ws[WS_SYBF + idx] = (syb[idx] - sybn[128 + idx]) * sy + sybn[64 + idx];
        float sl = lbn[idx] * rsqrtf(lbn[192 + idx] + EPS);
        ws[WS_LBF + idx] = (lb[idx] - lbn[128 + idx]) * sl + lbn[64 + idx];
    }
}

// ------------------------------------------------------------------
// gap: per (b,c) mean over 256x256
// ------------------------------------------------------------------
__global__ void gap_kernel(const float* __restrict__ x, float* __restrict__ ws) {
    int bc = blockIdx.x; // b*32+c
    const float* p = x + (size_t)bc * (HH * WW);
    float s = 0.f;
    for (int i = threadIdx.x; i < HH * WW; i += 256) s += p[i];
    #pragma unroll
    for (int off = 32; off; off >>= 1) s += __shfl_down(s, off, 64);
    __shared__ float red[4];
    int lane = threadIdx.x & 63, w = threadIdx.x >> 6;
    if (lane == 0) red[w] = s;
    __syncthreads();
    if (threadIdx.x == 0)
        ws[WS_GAP + bc] = (red[0] + red[1] + red[2] + red[3]) * (1.f / (HH * WW));
}

// ------------------------------------------------------------------
// gate: MLP + argmax -> bidx[8]
// ------------------------------------------------------------------
__global__ void gate_kernel(const float* __restrict__ w1, const float* __restrict__ b1,
                            const float* __restrict__ gbn,
                            const float* __restrict__ w2, const float* __restrict__ b2,
                            float* __restrict__ ws) {
    __shared__ float hsh[8][32];
    int tid = threadIdx.x;
    int b = tid >> 5, j = tid & 31;
    float acc = b1[j];
    for (int i = 0; i < 32; i++) acc += ws[WS_GAP + b * 32 + i] * w1[j * 32 + i];
    float s = gbn[j] * rsqrtf(gbn[96 + j] + EPS);
    hsh[b][j] = tanhf((acc - gbn[64 + j]) * s + gbn[32 + j]);
    __syncthreads();
    if (tid < 8) {
        float best = -1e30f; int bi = 0;
        for (int c = 0; c < 3; c++) {
            float k = b2[c];
            for (int jj = 0; jj < 32; jj++) k += hsh[tid][jj] * w2[c * 32 + jj];
            if (k > best) { best = k; bi = c; }
        }
        ((int*)ws)[WS_BIDX + tid] = bi;
    }
}

// ------------------------------------------------------------------
// main branch: fused conv3x3+bn+relu -> conv5x5+bn+relu
// 16x16 tile, 64 oc per block, 8oc x 8px per thread
// ------------------------------------------------------------------
__global__ void __launch_bounds__(256, 2)
main_kernel(const float* __restrict__ x, const float* __restrict__ ws, float* __restrict__ out) {
    __shared__ float xs[IC * 484];  // 32 x 22x22
    __shared__ float ys[8 * 400];   // 8ch x 20x20
    int b = blockIdx.y;
    if (((const int*)ws)[WS_BIDX + b] != 0) return;
    int tile = blockIdx.x;
    int ty = (tile >> 4) * 16, tx = (tile & 15) * 16;
    int tid = threadIdx.x;

    const float* xb = x + (size_t)b * IC * HH * WW;
    for (int i = tid; i < IC * 484; i += 256) {
        int ic = i / 484, rem = i % 484, rr = rem / 22, cc = rem % 22;
        int gy = ty - 3 + rr, gx = tx - 3 + cc;
        float v = 0.f;
        if ((unsigned)gy < HH && (unsigned)gx < WW) v = xb[(size_t)ic * HH * WW + gy * WW + gx];
        xs[i] = v;
    }

    float acc[8][8];
    #pragma unroll
    for (int o = 0; o < 8; o++)
        #pragma unroll
        for (int j = 0; j < 8; j++) acc[o][j] = 0.f;

    int ocg = tid >> 5;            // 8 groups of 8 oc
    int ps  = tid & 31;
    int row = ps >> 1, c0 = (ps & 1) * 8;
    const float* w1t = ws + WS_W1T;
    const float* b1f = ws + WS_B1F;
    const float* w2t = ws + WS_W2T;
    const float* b2f = ws + WS_B2F;

    __syncthreads();

    for (int icc = 0; icc < 8; icc++) {
        if (icc) __syncthreads();   // previous conv2 reads done before ys overwrite
        // conv1 for channels icc*8 .. icc*8+7 into ys
        for (int p = tid; p < 400; p += 256) {
            int r = p / 20, c = p % 20;
            bool inb = ((unsigned)(ty - 2 + r) < HH) && ((unsigned)(tx - 2 + c) < WW);
            float a1[8];
            #pragma unroll
            for (int ch = 0; ch < 8; ch++) a1[ch] = b1f[icc * 8 + ch];
            for (int ic = 0; ic < IC; ic++) {
                const float* xrow = xs + ic * 484 + r * 22 + c;
                #pragma unroll
                for (int kr = 0; kr < 3; kr++) {
                    #pragma unroll
                    for (int kc = 0; kc < 3; kc++) {
                        float xv = xrow[kr * 22 + kc];
                        const float4* wp = (const float4*)(w1t + (ic * 9 + kr * 3 + kc) * 64 + icc * 8);
                        float4 wa = wp[0], wb = wp[1];
                        a1[0] += xv * wa.x; a1[1] += xv * wa.y; a1[2] += xv * wa.z; a1[3] += xv * wa.w;
                        a1[4] += xv * wb.x; a1[5] += xv * wb.y; a1[6] += xv * wb.z; a1[7] += xv * wb.w;
                    }
                }
            }
            #pragma unroll
            for (int ch = 0; ch < 8; ch++)
                ys[ch * 400 + p] = inb ? fmaxf(a1[ch], 0.f) : 0.f;
        }
        __syncthreads();
        // conv2 accumulate over these 8 intermediate channels
        for (int ic8 = 0; ic8 < 8; ic8++) {
            const float* yc = ys + ic8 * 400;
            const float* wbase = w2t + ((icc * 8 + ic8) * 25) * 64 + ocg * 8;
            #pragma unroll
            for (int dh = 0; dh < 5; dh++) {
                #pragma unroll
                for (int dw = 0; dw < 5; dw++) {
                    const float* yp = yc + (row + dh) * 20 + c0 + dw;
                    float yv[8];
                    #pragma unroll
                    for (int j = 0; j < 8; j++) yv[j] = yp[j];
                    const float4* wp = (const float4*)(wbase + (dh * 5 + dw) * 64);
                    float4 wa = wp[0], wb = wp[1];
                    float wr[8] = {wa.x, wa.y, wa.z, wa.w, wb.x, wb.y, wb.z, wb.w};
                    #pragma unroll
                    for (int o = 0; o < 8; o++)
                        #pragma unroll
                        for (int j = 0; j < 8; j++) acc[o][j] += wr[o] * yv[j];
                }
            }
        }
    }
    // epilogue
    float* ob = out + (size_t)b * OC * HH * WW;
    #pragma unroll
    for (int o = 0; o < 8; o++) {
        int oc = ocg * 8 + o;
        float bb = b2f[oc];
        float* op = ob + (size_t)oc * HH * WW + (ty + row) * WW + tx + c0;
        #pragma unroll
        for (int j = 0; j < 8; j++) op[j] = fmaxf(acc[o][j] + bb, 0.f);
    }
}

// ------------------------------------------------------------------
// edge branches: fused depthwise3x3 (constexpr taps) -> conv5x5+bn+relu
// KID: 0=sobel_x, 1=sobel_y, 2=laplacian
// ------------------------------------------------------------------
template <int KID>
__global__ void __launch_bounds__(256, 2)
edge_kernel(const float* __restrict__ x, const float* __restrict__ ws, float* __restrict__ out,
            int want, float scale, int accumulate, int wt_off, int bf_off) {
    constexpr float KSX[9] = {1, 0, -1, 2, 0, -2, 1, 0, -1};
    constexpr float KSY[9] = {1, 2, 1, 0, 0, 0, -1, -2, -1};
    constexpr float KLP[9] = {0, 1, 0, 1, -4, 1, 0, 1, 0};

    __shared__ float xs[8 * 484];
    __shared__ float ys[8 * 400];
    int b = blockIdx.y;
    if (((const int*)ws)[WS_BIDX + b] != want) return;
    int tile = blockIdx.x;
    int ty = (tile >> 4) * 16, tx = (tile & 15) * 16;
    int tid = threadIdx.x;

    const float* xb = x + (size_t)b * IC * HH * WW;
    const float* wt = ws + wt_off;
    const float* bf = ws + bf_off;

    float acc[8][8];
    #pragma unroll
    for (int o = 0; o < 8; o++)
        #pragma unroll
        for (int j = 0; j < 8; j++) acc[o][j] = 0.f;

    int ocg = tid >> 5;
    int ps  = tid & 31;
    int row = ps >> 1, c0 = (ps & 1) * 8;

    for (int icc = 0; icc < 4; icc++) {
        if (icc) __syncthreads();
        // stage 8 input channels
        for (int i = tid; i < 8 * 484; i += 256) {
            int ch = i / 484, rem = i % 484, rr = rem / 22, cc = rem % 22;
            int ic = icc * 8 + ch;
            int gy = ty - 3 + rr, gx = tx - 3 + cc;
            float v = 0.f;
            if ((unsigned)gy < HH && (unsigned)gx < WW) v = xb[(size_t)ic * HH * WW + gy * WW + gx];
            xs[i] = v;
        }
        __syncthreads();
        // depthwise into ys (zero outside image: conv5's padding of the intermediate)
        for (int p = tid; p < 400; p += 256) {
            int r = p / 20, c = p % 20;
            bool inb = ((unsigned)(ty - 2 + r) < HH) && ((unsigned)(tx - 2 + c) < WW);
            #pragma unroll
            for (int ch = 0; ch < 8; ch++) {
                const float* xp = xs + ch * 484 + r * 22 + c;
                float v = 0.f;
                #pragma unroll
                for (int k = 0; k < 9; k++) {
                    float kv = (KID == 0) ? KSX[k] : (KID == 1) ? KSY[k] : KLP[k];
                    if (kv != 0.f) v += kv * xp[(k / 3) * 22 + (k % 3)];
                }
                ys[ch * 400 + p] = inb ? v : 0.f;
            }
        }
        __syncthreads();
        // conv5x5 accumulate
        for (int ic8 = 0; ic8 < 8; ic8++) {
            const float* yc = ys + ic8 * 400;
            const float* wbase = wt + ((icc * 8 + ic8) * 25) * 64 + ocg * 8;
            #pragma unroll
            for (int dh = 0; dh < 5; dh++) {
                #pragma unroll
                for (int dw = 0; dw < 5; dw++) {
                    const float* yp = yc + (row + dh) * 20 + c0 + dw;
                    float yv[8];
                    #pragma unroll
                    for (int j = 0; j < 8; j++) yv[j] = yp[j];
                    const float4* wp = (const float4*)(wbase + (dh * 5 + dw) * 64);
                    float4 wa = wp[0], wb = wp[1];
                    float wr[8] = {wa.x, wa.y, wa.z, wa.w, wb.x, wb.y, wb.z, wb.w};
                    #pragma unroll
                    for (int o = 0; o < 8; o++)
                        #pragma unroll
                        for (int j = 0; j < 8; j++) acc[o][j] += wr[o] * yv[j];
                }
            }
        }
    }
    float* ob = out + (size_t)b * OC * HH * WW;
    #pragma unroll
    for (int o = 0; o < 8; o++) {
        int oc = ocg * 8 + o;
        float bb = bf[oc];
        float* op = ob + (size_t)oc * HH * WW + (ty + row) * WW + tx + c0;
        if (accumulate) {
            #pragma unroll
            for (int j = 0; j < 8; j++) op[j] += scale * fmaxf(acc[o][j] + bb, 0.f);
        } else {
            #pragma unroll
            for (int j = 0; j < 8; j++) op[j] = scale * fmaxf(acc[o][j] + bb, 0.f);
        }
    }
}

// ------------------------------------------------------------------
extern "C" void kernel_launch(void* const* d_in, const int* in_sizes, int n_in,
                              void* d_out, int out_size, void* d_ws, size_t ws_size,
                              hipStream_t stream) {
    const float* x    = (const float*)d_in[0];
    const float* gw1  = (const float*)d_in[1];
    const float* gb1  = (const float*)d_in[2];
    const float* gbn  = (const float*)d_in[3];
    const float* gw2  = (const float*)d_in[4];
    const float* gb2  = (const float*)d_in[5];
    const float* mw1  = (const float*)d_in[6];
    const float* mb1  = (const float*)d_in[7];
    const float* mbn1 = (const float*)d_in[8];
    const float* mw2  = (const float*)d_in[9];
    const float* mb2  = (const float*)d_in[10];
    const float* mbn2 = (const float*)d_in[11];
    const float* sxw  = (const float*)d_in[12];
    const float* sxb  = (const float*)d_in[13];
    const float* sxbn = (const float*)d_in[14];
    const float* syw  = (const float*)d_in[15];
    const float* syb  = (const float*)d_in[16];
    const float* sybn = (const float*)d_in[17];
    const float* lw   = (const float*)d_in[18];
    const float* lb   = (const float*)d_in[19];
    const float* lbn  = (const float*)d_in[20];
    float* ws  = (float*)d_ws;
    float* out = (float*)d_out;

    prep_kernel<<<400, 256, 0, stream>>>(mw1, mb1, mbn1, mw2, mb2, mbn2,
                                         sxw, sxb, sxbn, syw, syb, sybn, lw, lb, lbn, ws);
    gap_kernel<<<256, 256, 0, stream>>>(x, ws);
    gate_kernel<<<1, 256, 0, stream>>>(gw1, gb1, gbn, gw2, gb2, ws);

    dim3 grid(256, BB);
    main_kernel<<<grid, 256, 0, stream>>>(x, ws, out);
    edge_kernel<0><<<grid, 256, 0, stream>>>(x, ws, out, 1, 0.5f, 0, WS_SXWT, WS_SXBF);
    edge_kernel<1><<<grid, 256, 0, stream>>>(x, ws, out, 1, 0.5f, 1, WS_SYWT, WS_SYBF);
    edge_kernel<2><<<grid, 256, 0, stream>>>(x, ws, out, 2, 1.0f, 0, WS_LWT, WS_LBF);
}

// Round 2
// 508.534 us; speedup vs baseline: 4.2315x; 4.2315x over previous
//
#include <hip/hip_runtime.h>

#define BB 8
#define IC 32
#define OC 64
#define HH 256
#define WW 256
#define EPS 1e-5f

typedef __attribute__((ext_vector_type(8))) short bf16x8;
typedef __attribute__((ext_vector_type(4))) float f32x4;

#define XSTR 40   // xs per-pixel stride in shorts (32 ic + 8 pad, 16B-aligned frags)
#define YSTR 40   // ys per-pixel stride in shorts (32 ic + 8 pad)

// ---- workspace layout (float indices) ----
#define WS_GAP   0                      // 256
#define WS_BIDX  256                    // 8 ints
#define WS_W1F   264                    // 18432 bf16 = 9216 floats (conv1 A-frags)
#define WS_B1F   (WS_W1F + 9216)        // 64
#define WS_W2F   (WS_B1F + 64)          // 102400 bf16 = 51200 floats (conv2 A-frags)
#define WS_B2F   (WS_W2F + 51200)       // 64
#define WS_SXWT  (WS_B2F + 64)          // 51200 (fp32 [ic][k][oc], edge branch)
#define WS_SXBF  (WS_SXWT + 51200)      // 64
#define WS_SYWT  (WS_SXBF + 64)         // 51200
#define WS_SYBF  (WS_SYWT + 51200)      // 64
#define WS_LWT   (WS_SYBF + 64)         // 51200
#define WS_LBF   (WS_LWT + 51200)       // 64

__device__ inline unsigned short bf16r(float f) {
    unsigned int u = __float_as_uint(f);
    unsigned int r = (u + 0x7fffu + ((u >> 16) & 1u)) >> 16;
    return (unsigned short)r;
}

// ------------------------------------------------------------------
// prep: fold BN scales into weights; conv1/conv2 weights emitted as bf16
// MFMA A-fragments (lane-major, 16B per lane, contiguous).
//   W1F idx = (((h*9+t)*2 + oct)*64 + lane)*8 + j
//       value = mw1[oc = h*32+oct*16+(lane&15)][ic = (lane>>4)*8+j][t] * s1[oc]
//   W2F idx = (((h*25+t)*4 + oct)*64 + lane)*8 + j
//       value = mw2[oc = oct*16+(lane&15)][ic = h*32+(lane>>4)*8+j][t] * s2[oc]
// ------------------------------------------------------------------
__global__ void prep_kernel(const float* __restrict__ mw1, const float* __restrict__ mb1, const float* __restrict__ mbn1,
                            const float* __restrict__ mw2, const float* __restrict__ mb2, const float* __restrict__ mbn2,
                            const float* __restrict__ sxw, const float* __restrict__ sxb, const float* __restrict__ sxbn,
                            const float* __restrict__ syw, const float* __restrict__ syb, const float* __restrict__ sybn,
                            const float* __restrict__ lw,  const float* __restrict__ lb,  const float* __restrict__ lbn,
                            float* __restrict__ ws) {
    int idx = blockIdx.x * 256 + threadIdx.x;

    if (idx < 18432) {  // conv1 A-frags
        int j = idx & 7, lane = (idx >> 3) & 63, oct = (idx >> 9) & 1, ht = idx >> 10;
        int t = ht % 9, h = ht / 9;
        int oc = h * 32 + oct * 16 + (lane & 15);
        int ic = (lane >> 4) * 8 + j;
        float s = mbn1[oc] * rsqrtf(mbn1[192 + oc] + EPS);
        ((unsigned short*)(ws + WS_W1F))[idx] = bf16r(mw1[(oc * IC + ic) * 9 + t] * s);
    }
    if (idx < 102400) {  // conv2 A-frags
        int j = idx & 7, lane = (idx >> 3) & 63, oct = (idx >> 9) & 3, ht = idx >> 11;
        int t = ht % 25, h = ht / 25;
        int oc = oct * 16 + (lane & 15);
        int ic = h * 32 + (lane >> 4) * 8 + j;
        float s = mbn2[oc] * rsqrtf(mbn2[192 + oc] + EPS);
        ((unsigned short*)(ws + WS_W2F))[idx] = bf16r(mw2[(oc * OC + ic) * 25 + t] * s);
    }
    if (idx < 51200) {  // edge-branch fp32 transposed weights [ic][k][oc]
        int oc = idx & 63, k = (idx >> 6) % 25, ic = idx / (25 * 64);
        float ssx = sxbn[oc] * rsqrtf(sxbn[192 + oc] + EPS);
        float ssy = sybn[oc] * rsqrtf(sybn[192 + oc] + EPS);
        float sl  = lbn[oc]  * rsqrtf(lbn[192 + oc]  + EPS);
        ws[WS_SXWT + idx] = sxw[(oc * IC + ic) * 25 + k] * ssx;
        ws[WS_SYWT + idx] = syw[(oc * IC + ic) * 25 + k] * ssy;
        ws[WS_LWT  + idx] = lw [(oc * IC + ic) * 25 + k] * sl;
    }
    if (idx < 64) {
        float s1 = mbn1[idx] * rsqrtf(mbn1[192 + idx] + EPS);
        ws[WS_B1F + idx] = (mb1[idx] - mbn1[128 + idx]) * s1 + mbn1[64 + idx];
        float s2 = mbn2[idx] * rsqrtf(mbn2[192 + idx] + EPS);
        ws[WS_B2F + idx] = (mb2[idx] - mbn2[128 + idx]) * s2 + mbn2[64 + idx];
        float sx = sxbn[idx] * rsqrtf(sxbn[192 + idx] + EPS);
        ws[WS_SXBF + idx] = (sxb[idx] - sxbn[128 + idx]) * sx + sxbn[64 + idx];
        float sy = sybn[idx] * rsqrtf(sybn[192 + idx] + EPS);
        ws[WS_SYBF + idx] = (syb[idx] - sybn[128 + idx]) * sy + sybn[64 + idx];
        float sl = lbn[idx] * rsqrtf(lbn[192 + idx] + EPS);
        ws[WS_LBF + idx] = (lb[idx] - lbn[128 + idx]) * sl + lbn[64 + idx];
    }
}

// ------------------------------------------------------------------
__global__ void gap_kernel(const float* __restrict__ x, float* __restrict__ ws) {
    int bc = blockIdx.x;
    const float* p = x + (size_t)bc * (HH * WW);
    float s = 0.f;
    for (int i = threadIdx.x; i < HH * WW; i += 256) s += p[i];
    #pragma unroll
    for (int off = 32; off; off >>= 1) s += __shfl_down(s, off, 64);
    __shared__ float red[4];
    int lane = threadIdx.x & 63, w = threadIdx.x >> 6;
    if (lane == 0) red[w] = s;
    __syncthreads();
    if (threadIdx.x == 0)
        ws[WS_GAP + bc] = (red[0] + red[1] + red[2] + red[3]) * (1.f / (HH * WW));
}

__global__ void gate_kernel(const float* __restrict__ w1, const float* __restrict__ b1,
                            const float* __restrict__ gbn,
                            const float* __restrict__ w2, const float* __restrict__ b2,
                            float* __restrict__ ws) {
    __shared__ float hsh[8][32];
    int tid = threadIdx.x;
    int b = tid >> 5, j = tid & 31;
    float acc = b1[j];
    for (int i = 0; i < 32; i++) acc += ws[WS_GAP + b * 32 + i] * w1[j * 32 + i];
    float s = gbn[j] * rsqrtf(gbn[96 + j] + EPS);
    hsh[b][j] = tanhf((acc - gbn[64 + j]) * s + gbn[32 + j]);
    __syncthreads();
    if (tid < 8) {
        float best = -1e30f; int bi = 0;
        for (int c = 0; c < 3; c++) {
            float k = b2[c];
            for (int jj = 0; jj < 32; jj++) k += hsh[tid][jj] * w2[c * 32 + jj];
            if (k > best) { best = k; bi = c; }
        }
        ((int*)ws)[WS_BIDX + tid] = bi;
    }
}

// ------------------------------------------------------------------
// main branch: fused conv3x3+bn+relu -> conv5x5+bn+relu via bf16 MFMA.
// Block = 16x16 output tile x 64 oc, 4 waves.
//   conv as shifted GEMMs, K = input channels.
//   xs: [22x22 px][32 ic] bf16, stride 40  (38720 B)
//   ys: [20x20 px][32 ic-half] bf16, stride 40 (32000 B)   -> 70.7 KB, 2 blk/CU
// conv1 runs in two 32-oc halves; conv2 consumes each half as one K=32 step.
// MFMA 16x16x32 layouts (m89-verified): A[m=lane&15][k=quad*8+j],
// B[k=quad*8+j][n=lane&15], D: col=lane&15, row=quad*4+reg.
// ------------------------------------------------------------------
__global__ void __launch_bounds__(256, 2)
main_kernel(const float* __restrict__ x, const float* __restrict__ ws, float* __restrict__ out) {
    __shared__ __align__(16) short xs[484 * XSTR];
    __shared__ __align__(16) short ys[400 * YSTR];

    int b = blockIdx.y;
    if (((const int*)ws)[WS_BIDX + b] != 0) return;
    int tile = blockIdx.x;
    int ty = (tile >> 4) * 16, tx = (tile & 15) * 16;
    int tid = threadIdx.x;
    int w = tid >> 6, lane = tid & 63, n = lane & 15, quad = lane >> 4;

    // ---- stage x tile as bf16, [pixel][ic] ----
    const float* xb = x + (size_t)b * IC * HH * WW;
    for (int p = tid; p < 484; p += 256) {
        int rr = p / 22, cc = p % 22;
        int gy = ty - 3 + rr, gx = tx - 3 + cc;
        bool v = ((unsigned)gy < HH) && ((unsigned)gx < WW);
        const float* xp = xb + gy * WW + gx;
        short* dst = xs + p * XSTR;
        #pragma unroll
        for (int ic = 0; ic < IC; ic += 2) {
            float f0 = v ? xp[(size_t)ic * (HH * WW)] : 0.f;
            float f1 = v ? xp[(size_t)(ic + 1) * (HH * WW)] : 0.f;
            unsigned int pk = (unsigned int)bf16r(f0) | ((unsigned int)bf16r(f1) << 16);
            *(unsigned int*)(dst + ic) = pk;
        }
    }

    const short* w1v = (const short*)(ws + WS_W1F);
    const bf16x8* w2v = (const bf16x8*)(ws + WS_W2F);

    // conv2 accumulators: 4 rows x 4 oc-tiles (held across both halves)
    f32x4 acc2[4][4];
    #pragma unroll
    for (int i = 0; i < 4; i++)
        #pragma unroll
        for (int jj = 0; jj < 4; jj++) acc2[i][jj] = (f32x4){0.f, 0.f, 0.f, 0.f};
    int mrow0 = w * 4;  // this wave's 4 output rows

    __syncthreads();

    for (int h = 0; h < 2; h++) {
        if (h) __syncthreads();  // conv2 reads of prev half done before ys overwrite

        // ---- conv1 half h: Y[20x20][32] for conv1 oc = h*32 .. h*32+31 ----
        // wave w owns Y rows w*5 .. w*5+4; col-groups {0..15} and {4..19} (overlap benign)
        #pragma unroll
        for (int oct = 0; oct < 2; oct++) {
            bf16x8 w1f[9];
            #pragma unroll
            for (int t = 0; t < 9; t++)
                w1f[t] = *(const bf16x8*)(w1v + (((h * 9 + t) * 2 + oct) * 64 + lane) * 8);
            float bias1[4];
            #pragma unroll
            for (int r = 0; r < 4; r++)
                bias1[r] = ws[WS_B1F + h * 32 + oct * 16 + quad * 4 + r];

            for (int rr = 0; rr < 5; rr++) {
                int yr = w * 5 + rr;
                int gy2 = ty - 2 + yr;
                #pragma unroll
                for (int cg = 0; cg < 2; cg++) {
                    int cb = cg * 4;
                    f32x4 a = (f32x4){0.f, 0.f, 0.f, 0.f};
                    #pragma unroll
                    for (int t = 0; t < 9; t++) {
                        int dh = t / 3, dw = t % 3;
                        bf16x8 bf = *(const bf16x8*)(xs + ((yr + dh) * 22 + cb + n + dw) * XSTR + quad * 8);
                        a = __builtin_amdgcn_mfma_f32_16x16x32_bf16(w1f[t], bf, a, 0, 0, 0);
                    }
                    int gx2 = tx - 2 + cb + n;
                    bool inb = ((unsigned)gy2 < HH) && ((unsigned)gx2 < WW);
                    float v0 = inb ? fmaxf(a[0] + bias1[0], 0.f) : 0.f;
                    float v1 = inb ? fmaxf(a[1] + bias1[1], 0.f) : 0.f;
                    float v2 = inb ? fmaxf(a[2] + bias1[2], 0.f) : 0.f;
                    float v3 = inb ? fmaxf(a[3] + bias1[3], 0.f) : 0.f;
                    int p = yr * 20 + cb + n;
                    uint2 pk;
                    pk.x = (unsigned int)bf16r(v0) | ((unsigned int)bf16r(v1) << 16);
                    pk.y = (unsigned int)bf16r(v2) | ((unsigned int)bf16r(v3) << 16);
                    *(uint2*)(ys + p * YSTR + oct * 16 + quad * 4) = pk;
                }
            }
        }
        __syncthreads();

        // ---- conv2 partial: K-step = this half's 32 channels, 25 taps ----
        bf16x8 af0 = w2v[(h * 25 * 4 + 0) * 64 + lane];
        bf16x8 af1 = w2v[(h * 25 * 4 + 1) * 64 + lane];
        bf16x8 af2 = w2v[(h * 25 * 4 + 2) * 64 + lane];
        bf16x8 af3 = w2v[(h * 25 * 4 + 3) * 64 + lane];
        for (int t = 0; t < 25; t++) {
            int dh = t / 5, dw = t % 5;
            bf16x8 an0, an1, an2, an3;
            if (t < 24) {
                int base = ((h * 25 + t + 1) * 4) * 64 + lane;
                an0 = w2v[base]; an1 = w2v[base + 64]; an2 = w2v[base + 128]; an3 = w2v[base + 192];
            }
            #pragma unroll
            for (int r4 = 0; r4 < 4; r4++) {
                int p = (mrow0 + r4 + dh) * 20 + n + dw;
                bf16x8 bf = *(const bf16x8*)(ys + p * YSTR + quad * 8);
                acc2[r4][0] = __builtin_amdgcn_mfma_f32_16x16x32_bf16(af0, bf, acc2[r4][0], 0, 0, 0);
                acc2[r4][1] = __builtin_amdgcn_mfma_f32_16x16x32_bf16(af1, bf, acc2[r4][1], 0, 0, 0);
                acc2[r4][2] = __builtin_amdgcn_mfma_f32_16x16x32_bf16(af2, bf, acc2[r4][2], 0, 0, 0);
                acc2[r4][3] = __builtin_amdgcn_mfma_f32_16x16x32_bf16(af3, bf, acc2[r4][3], 0, 0, 0);
            }
            af0 = an0; af1 = an1; af2 = an2; af3 = an3;
        }
    }

    // ---- epilogue: relu(acc + b2f), store ----
    float bias2[4][4];
    #pragma unroll
    for (int oct = 0; oct < 4; oct++)
        #pragma unroll
        for (int r = 0; r < 4; r++)
            bias2[oct][r] = ws[WS_B2F + oct * 16 + quad * 4 + r];

    float* ob = out + (size_t)b * OC * HH * WW;
    #pragma unroll
    for (int r4 = 0; r4 < 4; r4++) {
        int orow = mrow0 + r4;
        #pragma unroll
        for (int oct = 0; oct < 4; oct++) {
            #pragma unroll
            for (int r = 0; r < 4; r++) {
                int oc = oct * 16 + quad * 4 + r;
                float v = fmaxf(acc2[r4][oct][r] + bias2[oct][r], 0.f);
                ob[(size_t)oc * (HH * WW) + (ty + orow) * WW + tx + n] = v;
            }
        }
    }
}

// ------------------------------------------------------------------
// edge branches (fp32; early-exit — not selected by this seed's gate)
// ------------------------------------------------------------------
template <int KID>
__global__ void __launch_bounds__(256, 2)
edge_kernel(const float* __restrict__ x, const float* __restrict__ ws, float* __restrict__ out,
            int want, float scale, int accumulate, int wt_off, int bf_off) {
    constexpr float KSX[9] = {1, 0, -1, 2, 0, -2, 1, 0, -1};
    constexpr float KSY[9] = {1, 2, 1, 0, 0, 0, -1, -2, -1};
    constexpr float KLP[9] = {0, 1, 0, 1, -4, 1, 0, 1, 0};

    __shared__ float xsf[8 * 484];
    __shared__ float ysf[8 * 400];
    int b = blockIdx.y;
    if (((const int*)ws)[WS_BIDX + b] != want) return;
    int tile = blockIdx.x;
    int ty = (tile >> 4) * 16, tx = (tile & 15) * 16;
    int tid = threadIdx.x;

    const float* xb = x + (size_t)b * IC * HH * WW;
    const float* wt = ws + wt_off;
    const float* bf = ws + bf_off;

    float acc[8][8];
    #pragma unroll
    for (int o = 0; o < 8; o++)
        #pragma unroll
        for (int j = 0; j < 8; j++) acc[o][j] = 0.f;

    int ocg = tid >> 5;
    int ps  = tid & 31;
    int row = ps >> 1, c0 = (ps & 1) * 8;

    for (int icc = 0; icc < 4; icc++) {
        if (icc) __syncthreads();
        for (int i = tid; i < 8 * 484; i += 256) {
            int ch = i / 484, rem = i % 484, rr = rem / 22, cc = rem % 22;
            int ic = icc * 8 + ch;
            int gy = ty - 3 + rr, gx = tx - 3 + cc;
            float v = 0.f;
            if ((unsigned)gy < HH && (unsigned)gx < WW) v = xb[(size_t)ic * HH * WW + gy * WW + gx];
            xsf[i] = v;
        }
        __syncthreads();
        for (int p = tid; p < 400; p += 256) {
            int r = p / 20, c = p % 20;
            bool inb = ((unsigned)(ty - 2 + r) < HH) && ((unsigned)(tx - 2 + c) < WW);
            #pragma unroll
            for (int ch = 0; ch < 8; ch++) {
                const float* xp = xsf + ch * 484 + r * 22 + c;
                float v = 0.f;
                #pragma unroll
                for (int k = 0; k < 9; k++) {
                    float kv = (KID == 0) ? KSX[k] : (KID == 1) ? KSY[k] : KLP[k];
                    if (kv != 0.f) v += kv * xp[(k / 3) * 22 + (k % 3)];
                }
                ysf[ch * 400 + p] = inb ? v : 0.f;
            }
        }
        __syncthreads();
        for (int ic8 = 0; ic8 < 8; ic8++) {
            const float* yc = ysf + ic8 * 400;
            const float* wbase = wt + ((icc * 8 + ic8) * 25) * 64 + ocg * 8;
            #pragma unroll
            for (int dh = 0; dh < 5; dh++) {
                #pragma unroll
                for (int dw = 0; dw < 5; dw++) {
                    const float* yp = yc + (row + dh) * 20 + c0 + dw;
                    float yv[8];
                    #pragma unroll
                    for (int j = 0; j < 8; j++) yv[j] = yp[j];
                    const float4* wp = (const float4*)(wbase + (dh * 5 + dw) * 64);
                    float4 wa = wp[0], wb = wp[1];
                    float wr[8] = {wa.x, wa.y, wa.z, wa.w, wb.x, wb.y, wb.z, wb.w};
                    #pragma unroll
                    for (int o = 0; o < 8; o++)
                        #pragma unroll
                        for (int j = 0; j < 8; j++) acc[o][j] += wr[o] * yv[j];
                }
            }
        }
    }
    float* ob = out + (size_t)b * OC * HH * WW;
    #pragma unroll
    for (int o = 0; o < 8; o++) {
        int oc = ocg * 8 + o;
        float bb = bf[oc];
        float* op = ob + (size_t)oc * HH * WW + (ty + row) * WW + tx + c0;
        if (accumulate) {
            #pragma unroll
            for (int j = 0; j < 8; j++) op[j] += scale * fmaxf(acc[o][j] + bb, 0.f);
        } else {
            #pragma unroll
            for (int j = 0; j < 8; j++) op[j] = scale * fmaxf(acc[o][j] + bb, 0.f);
        }
    }
}

// ------------------------------------------------------------------
extern "C" void kernel_launch(void* const* d_in, const int* in_sizes, int n_in,
                              void* d_out, int out_size, void* d_ws, size_t ws_size,
                              hipStream_t stream) {
    const float* x    = (const float*)d_in[0];
    const float* gw1  = (const float*)d_in[1];
    const float* gb1  = (const float*)d_in[2];
    const float* gbn  = (const float*)d_in[3];
    const float* gw2  = (const float*)d_in[4];
    const float* gb2  = (const float*)d_in[5];
    const float* mw1  = (const float*)d_in[6];
    const float* mb1  = (const float*)d_in[7];
    const float* mbn1 = (const float*)d_in[8];
    const float* mw2  = (const float*)d_in[9];
    const float* mb2  = (const float*)d_in[10];
    const float* mbn2 = (const float*)d_in[11];
    const float* sxw  = (const float*)d_in[12];
    const float* sxb  = (const float*)d_in[13];
    const float* sxbn = (const float*)d_in[14];
    const float* syw  = (const float*)d_in[15];
    const float* syb  = (const float*)d_in[16];
    const float* sybn = (const float*)d_in[17];
    const float* lw   = (const float*)d_in[18];
    const float* lb   = (const float*)d_in[19];
    const float* lbn  = (const float*)d_in[20];
    float* ws  = (float*)d_ws;
    float* out = (float*)d_out;

    prep_kernel<<<400, 256, 0, stream>>>(mw1, mb1, mbn1, mw2, mb2, mbn2,
                                         sxw, sxb, sxbn, syw, syb, sybn, lw, lb, lbn, ws);
    gap_kernel<<<256, 256, 0, stream>>>(x, ws);
    gate_kernel<<<1, 256, 0, stream>>>(gw1, gb1, gbn, gw2, gb2, ws);

    dim3 grid(256, BB);
    main_kernel<<<grid, 256, 0, stream>>>(x, ws, out);
    edge_kernel<0><<<grid, 256, 0, stream>>>(x, ws, out, 1, 0.5f, 0, WS_SXWT, WS_SXBF);
    edge_kernel<1><<<grid, 256, 0, stream>>>(x, ws, out, 1, 0.5f, 1, WS_SYWT, WS_SYBF);
    edge_kernel<2><<<grid, 256, 0, stream>>>(x, ws, out, 2, 1.0f, 0, WS_LWT, WS_LBF);
}

// Round 3
// 426.435 us; speedup vs baseline: 5.0462x; 1.1925x over previous
//
#include <hip/hip_runtime.h>

#define BB 8
#define IC 32
#define OC 64
#define HH 256
#define WW 256
#define EPS 1e-5f

typedef __attribute__((ext_vector_type(8))) short bf16x8;
typedef __attribute__((ext_vector_type(4))) float f32x4;

#define XSTR 40   // xs per-pixel stride in shorts (32 ic + 8 pad, 16B-aligned frags)
#define YSTR 40   // ys per-pixel stride in shorts (32 ic + 8 pad)

// ---- workspace layout (float indices) ----
#define WS_GAP   0                      // 256
#define WS_BIDX  256                    // 8 ints
#define WS_W1F   264                    // 18432 bf16 = 9216 floats (conv1 A-frags)
#define WS_B1F   (WS_W1F + 9216)        // 64
#define WS_W2F   (WS_B1F + 64)          // 102400 bf16 = 51200 floats (conv2 A-frags)
#define WS_B2F   (WS_W2F + 51200)       // 64
#define WS_SXWT  (WS_B2F + 64)          // 51200 (fp32 [ic][k][oc], edge branch)
#define WS_SXBF  (WS_SXWT + 51200)      // 64
#define WS_SYWT  (WS_SXBF + 64)         // 51200
#define WS_SYBF  (WS_SYWT + 51200)      // 64
#define WS_LWT   (WS_SYBF + 64)         // 51200
#define WS_LBF   (WS_LWT + 51200)       // 64

__device__ inline unsigned short bf16r(float f) {
    unsigned int u = __float_as_uint(f);
    unsigned int r = (u + 0x7fffu + ((u >> 16) & 1u)) >> 16;
    return (unsigned short)r;
}

// ------------------------------------------------------------------
// prep: fold BN scales into weights; conv1/conv2 weights emitted as bf16
// MFMA A-fragments (lane-major, 16B per lane, contiguous).
//   W1F idx = (((h*9+t)*2 + oct)*64 + lane)*8 + j   (t = dh*3+dw)
//       value = mw1[oc = h*32+oct*16+(lane&15)][ic = (lane>>4)*8+j][t] * s1[oc]
//   W2F idx = (((h*25+t)*4 + oct)*64 + lane)*8 + j  (t = dh*5+dw)
//       value = mw2[oc = oct*16+(lane&15)][ic = h*32+(lane>>4)*8+j][t] * s2[oc]
// ------------------------------------------------------------------
__global__ void prep_kernel(const float* __restrict__ mw1, const float* __restrict__ mb1, const float* __restrict__ mbn1,
                            const float* __restrict__ mw2, const float* __restrict__ mb2, const float* __restrict__ mbn2,
                            const float* __restrict__ sxw, const float* __restrict__ sxb, const float* __restrict__ sxbn,
                            const float* __restrict__ syw, const float* __restrict__ syb, const float* __restrict__ sybn,
                            const float* __restrict__ lw,  const float* __restrict__ lb,  const float* __restrict__ lbn,
                            float* __restrict__ ws) {
    int idx = blockIdx.x * 256 + threadIdx.x;

    if (idx < 18432) {  // conv1 A-frags
        int j = idx & 7, lane = (idx >> 3) & 63, oct = (idx >> 9) & 1, ht = idx >> 10;
        int t = ht % 9, h = ht / 9;
        int oc = h * 32 + oct * 16 + (lane & 15);
        int ic = (lane >> 4) * 8 + j;
        float s = mbn1[oc] * rsqrtf(mbn1[192 + oc] + EPS);
        ((unsigned short*)(ws + WS_W1F))[idx] = bf16r(mw1[(oc * IC + ic) * 9 + t] * s);
    }
    if (idx < 102400) {  // conv2 A-frags
        int j = idx & 7, lane = (idx >> 3) & 63, oct = (idx >> 9) & 3, ht = idx >> 11;
        int t = ht % 25, h = ht / 25;
        int oc = oct * 16 + (lane & 15);
        int ic = h * 32 + (lane >> 4) * 8 + j;
        float s = mbn2[oc] * rsqrtf(mbn2[192 + oc] + EPS);
        ((unsigned short*)(ws + WS_W2F))[idx] = bf16r(mw2[(oc * OC + ic) * 25 + t] * s);
    }
    if (idx < 51200) {  // edge-branch fp32 transposed weights [ic][k][oc]
        int oc = idx & 63, k = (idx >> 6) % 25, ic = idx / (25 * 64);
        float ssx = sxbn[oc] * rsqrtf(sxbn[192 + oc] + EPS);
        float ssy = sybn[oc] * rsqrtf(sybn[192 + oc] + EPS);
        float sl  = lbn[oc]  * rsqrtf(lbn[192 + oc]  + EPS);
        ws[WS_SXWT + idx] = sxw[(oc * IC + ic) * 25 + k] * ssx;
        ws[WS_SYWT + idx] = syw[(oc * IC + ic) * 25 + k] * ssy;
        ws[WS_LWT  + idx] = lw [(oc * IC + ic) * 25 + k] * sl;
    }
    if (idx < 64) {
        float s1 = mbn1[idx] * rsqrtf(mbn1[192 + idx] + EPS);
        ws[WS_B1F + idx] = (mb1[idx] - mbn1[128 + idx]) * s1 + mbn1[64 + idx];
        float s2 = mbn2[idx] * rsqrtf(mbn2[192 + idx] + EPS);
        ws[WS_B2F + idx] = (mb2[idx] - mbn2[128 + idx]) * s2 + mbn2[64 + idx];
        float sx = sxbn[idx] * rsqrtf(sxbn[192 + idx] + EPS);
        ws[WS_SXBF + idx] = (sxb[idx] - sxbn[128 + idx]) * sx + sxbn[64 + idx];
        float sy = sybn[idx] * rsqrtf(sybn[192 + idx] + EPS);
        ws[WS_SYBF + idx] = (syb[idx] - sybn[128 + idx]) * sy + sybn[64 + idx];
        float sl = lbn[idx] * rsqrtf(lbn[192 + idx] + EPS);
        ws[WS_LBF + idx] = (lb[idx] - lbn[128 + idx]) * sl + lbn[64 + idx];
    }
}

// ------------------------------------------------------------------
__global__ void gap_kernel(const float* __restrict__ x, float* __restrict__ ws) {
    int bc = blockIdx.x;
    const float4* p = (const float4*)(x + (size_t)bc * (HH * WW));
    float s = 0.f;
    for (int i = threadIdx.x; i < (HH * WW) / 4; i += 256) {
        float4 v = p[i];
        s += (v.x + v.y) + (v.z + v.w);
    }
    #pragma unroll
    for (int off = 32; off; off >>= 1) s += __shfl_down(s, off, 64);
    __shared__ float red[4];
    int lane = threadIdx.x & 63, w = threadIdx.x >> 6;
    if (lane == 0) red[w] = s;
    __syncthreads();
    if (threadIdx.x == 0)
        ws[WS_GAP + bc] = (red[0] + red[1] + red[2] + red[3]) * (1.f / (HH * WW));
}

__global__ void gate_kernel(const float* __restrict__ w1, const float* __restrict__ b1,
                            const float* __restrict__ gbn,
                            const float* __restrict__ w2, const float* __restrict__ b2,
                            float* __restrict__ ws) {
    __shared__ float hsh[8][32];
    int tid = threadIdx.x;
    int b = tid >> 5, j = tid & 31;
    float acc = b1[j];
    for (int i = 0; i < 32; i++) acc += ws[WS_GAP + b * 32 + i] * w1[j * 32 + i];
    float s = gbn[j] * rsqrtf(gbn[96 + j] + EPS);
    hsh[b][j] = tanhf((acc - gbn[64 + j]) * s + gbn[32 + j]);
    __syncthreads();
    if (tid < 8) {
        float best = -1e30f; int bi = 0;
        for (int c = 0; c < 3; c++) {
            float k = b2[c];
            for (int jj = 0; jj < 32; jj++) k += hsh[tid][jj] * w2[c * 32 + jj];
            if (k > best) { best = k; bi = c; }
        }
        ((int*)ws)[WS_BIDX + tid] = bi;
    }
}

// ------------------------------------------------------------------
// main branch: fused conv3x3+bn+relu -> conv5x5+bn+relu via bf16 MFMA.
// Block = 16x16 output tile x 64 oc, 4 waves. K = input channels.
//   xs: [22x22 px][32 ic] bf16, stride 40  (38720 B)
//   ys: [20x20 px][32 half-ch] bf16, stride 40 (32000 B)  -> 70.7 KB, 2 blk/CU
// R3 restructure: B-fragments register-blocked so each ds_read_b128 feeds
// many MFMAs (conv1: 7 row-frags x 2 oc-tiles over 3 dh; conv2: 8 row-frags
// over 5 dh x 4 oc-tiles). LDS reads/wave: 560 -> 164.
// MFMA 16x16x32 layouts (m89): A[m=lane&15][k=quad*8+j],
// B[k=quad*8+j][n=lane&15], D: col=lane&15, row=quad*4+reg.
// ------------------------------------------------------------------
__global__ void __launch_bounds__(256, 2)
main_kernel(const float* __restrict__ x, const float* __restrict__ ws, float* __restrict__ out) {
    __shared__ __align__(16) short xs[484 * XSTR];
    __shared__ __align__(16) short ys[400 * YSTR];

    int b = blockIdx.y;
    if (((const int*)ws)[WS_BIDX + b] != 0) return;
    int tile = blockIdx.x;
    int ty = (tile >> 4) * 16, tx = (tile & 15) * 16;
    int tid = threadIdx.x;
    int w = tid >> 6, lane = tid & 63, n = lane & 15, quad = lane >> 4;

    // ---- stage x tile as bf16, [pixel][ic] ----
    const float* xb = x + (size_t)b * IC * HH * WW;
    for (int p = tid; p < 484; p += 256) {
        int rr = p / 22, cc = p % 22;
        int gy = ty - 3 + rr, gx = tx - 3 + cc;
        bool v = ((unsigned)gy < HH) && ((unsigned)gx < WW);
        const float* xp = xb + gy * WW + gx;
        short* dst = xs + p * XSTR;
        #pragma unroll
        for (int ic = 0; ic < IC; ic += 4) {
            float f0 = v ? xp[(size_t)(ic + 0) * (HH * WW)] : 0.f;
            float f1 = v ? xp[(size_t)(ic + 1) * (HH * WW)] : 0.f;
            float f2 = v ? xp[(size_t)(ic + 2) * (HH * WW)] : 0.f;
            float f3 = v ? xp[(size_t)(ic + 3) * (HH * WW)] : 0.f;
            uint2 pk;
            pk.x = (unsigned int)bf16r(f0) | ((unsigned int)bf16r(f1) << 16);
            pk.y = (unsigned int)bf16r(f2) | ((unsigned int)bf16r(f3) << 16);
            *(uint2*)(dst + ic) = pk;
        }
    }

    const short* w1v = (const short*)(ws + WS_W1F);
    const bf16x8* w2v = (const bf16x8*)(ws + WS_W2F);

    f32x4 acc2[4][4];
    #pragma unroll
    for (int i = 0; i < 4; i++)
        #pragma unroll
        for (int jj = 0; jj < 4; jj++) acc2[i][jj] = (f32x4){0.f, 0.f, 0.f, 0.f};
    int mrow0 = w * 4;   // conv2 output rows of this wave
    int yr0   = w * 5;   // conv1 output rows of this wave

    __syncthreads();

    #pragma unroll 1
    for (int h = 0; h < 2; h++) {
        if (h) __syncthreads();  // conv2 reads of prev half done before ys overwrite

        // ---- conv1 half h: Y[20x20][32] for conv1 oc = h*32 .. h*32+31 ----
        #pragma unroll
        for (int cg = 0; cg < 2; cg++) {
            int cb = cg * 4;
            f32x4 a1[5][2];
            #pragma unroll
            for (int rr = 0; rr < 5; rr++) {
                a1[rr][0] = (f32x4){0.f, 0.f, 0.f, 0.f};
                a1[rr][1] = (f32x4){0.f, 0.f, 0.f, 0.f};
            }
            #pragma unroll
            for (int dw = 0; dw < 3; dw++) {
                // A-frags for taps (dh=0..2, this dw), both oc-tiles
                bf16x8 w1f[3][2];
                #pragma unroll
                for (int dh = 0; dh < 3; dh++) {
                    int t = dh * 3 + dw;
                    w1f[dh][0] = *(const bf16x8*)(w1v + (((h * 9 + t) * 2 + 0) * 64 + lane) * 8);
                    w1f[dh][1] = *(const bf16x8*)(w1v + (((h * 9 + t) * 2 + 1) * 64 + lane) * 8);
                }
                // B-frags: xs rows yr0..yr0+6 at col cb+n+dw
                bf16x8 bfr[7];
                #pragma unroll
                for (int rI = 0; rI < 7; rI++)
                    bfr[rI] = *(const bf16x8*)(xs + ((yr0 + rI) * 22 + cb + n + dw) * XSTR + quad * 8);
                #pragma unroll
                for (int dh = 0; dh < 3; dh++)
                    #pragma unroll
                    for (int rr = 0; rr < 5; rr++) {
                        a1[rr][0] = __builtin_amdgcn_mfma_f32_16x16x32_bf16(w1f[dh][0], bfr[rr + dh], a1[rr][0], 0, 0, 0);
                        a1[rr][1] = __builtin_amdgcn_mfma_f32_16x16x32_bf16(w1f[dh][1], bfr[rr + dh], a1[rr][1], 0, 0, 0);
                    }
            }
            // epilogue: relu(a1 + bias1) -> bf16 -> ys
            #pragma unroll
            for (int oct = 0; oct < 2; oct++) {
                float bias1[4];
                #pragma unroll
                for (int r = 0; r < 4; r++)
                    bias1[r] = ws[WS_B1F + h * 32 + oct * 16 + quad * 4 + r];
                #pragma unroll
                for (int rr = 0; rr < 5; rr++) {
                    int yr = yr0 + rr;
                    int gy2 = ty - 2 + yr, gx2 = tx - 2 + cb + n;
                    bool inb = ((unsigned)gy2 < HH) && ((unsigned)gx2 < WW);
                    float v0 = inb ? fmaxf(a1[rr][oct][0] + bias1[0], 0.f) : 0.f;
                    float v1 = inb ? fmaxf(a1[rr][oct][1] + bias1[1], 0.f) : 0.f;
                    float v2 = inb ? fmaxf(a1[rr][oct][2] + bias1[2], 0.f) : 0.f;
                    float v3 = inb ? fmaxf(a1[rr][oct][3] + bias1[3], 0.f) : 0.f;
                    uint2 pk;
                    pk.x = (unsigned int)bf16r(v0) | ((unsigned int)bf16r(v1) << 16);
                    pk.y = (unsigned int)bf16r(v2) | ((unsigned int)bf16r(v3) << 16);
                    *(uint2*)(ys + (yr * 20 + cb + n) * YSTR + oct * 16 + quad * 4) = pk;
                }
            }
        }
        __syncthreads();

        // ---- conv2 partial: K-step = this half's 32 channels, 25 taps ----
        const bf16x8* w2h = w2v + (size_t)h * 100 * 64;
        bf16x8 af[4];
        {
            int base = 0 * 64 + lane;  // k=0 -> dw=0,dh=0 -> t=0
            af[0] = w2h[base]; af[1] = w2h[base + 64]; af[2] = w2h[base + 128]; af[3] = w2h[base + 192];
        }
        bf16x8 bfr2[8];
        #pragma unroll
        for (int k = 0; k < 25; k++) {
            int dw = k / 5, dh = k % 5;
            if (dh == 0) {
                #pragma unroll
                for (int rI = 0; rI < 8; rI++)
                    bfr2[rI] = *(const bf16x8*)(ys + ((mrow0 + rI) * 20 + n + dw) * YSTR + quad * 8);
            }
            bf16x8 an[4];
            if (k < 24) {
                int kk = k + 1;
                int tn = (kk % 5) * 5 + (kk / 5);
                int base = tn * 4 * 64 + lane;
                an[0] = w2h[base]; an[1] = w2h[base + 64]; an[2] = w2h[base + 128]; an[3] = w2h[base + 192];
            }
            #pragma unroll
            for (int r4 = 0; r4 < 4; r4++) {
                bf16x8 bb = bfr2[r4 + dh];
                acc2[r4][0] = __builtin_amdgcn_mfma_f32_16x16x32_bf16(af[0], bb, acc2[r4][0], 0, 0, 0);
                acc2[r4][1] = __builtin_amdgcn_mfma_f32_16x16x32_bf16(af[1], bb, acc2[r4][1], 0, 0, 0);
                acc2[r4][2] = __builtin_amdgcn_mfma_f32_16x16x32_bf16(af[2], bb, acc2[r4][2], 0, 0, 0);
                acc2[r4][3] = __builtin_amdgcn_mfma_f32_16x16x32_bf16(af[3], bb, acc2[r4][3], 0, 0, 0);
            }
            af[0] = an[0]; af[1] = an[1]; af[2] = an[2]; af[3] = an[3];
        }
    }

    // ---- epilogue: relu(acc + b2f), store ----
    float bias2[4][4];
    #pragma unroll
    for (int oct = 0; oct < 4; oct++)
        #pragma unroll
        for (int r = 0; r < 4; r++)
            bias2[oct][r] = ws[WS_B2F + oct * 16 + quad * 4 + r];

    float* ob = out + (size_t)b * OC * HH * WW;
    #pragma unroll
    for (int r4 = 0; r4 < 4; r4++) {
        int orow = mrow0 + r4;
        #pragma unroll
        for (int oct = 0; oct < 4; oct++) {
            #pragma unroll
            for (int r = 0; r < 4; r++) {
                int oc = oct * 16 + quad * 4 + r;
                float v = fmaxf(acc2[r4][oct][r] + bias2[oct][r], 0.f);
                ob[(size_t)oc * (HH * WW) + (ty + orow) * WW + tx + n] = v;
            }
        }
    }
}

// ------------------------------------------------------------------
// edge branches (fp32; early-exit — not selected by this seed's gate)
// ------------------------------------------------------------------
template <int KID>
__global__ void __launch_bounds__(256, 2)
edge_kernel(const float* __restrict__ x, const float* __restrict__ ws, float* __restrict__ out,
            int want, float scale, int accumulate, int wt_off, int bf_off) {
    constexpr float KSX[9] = {1, 0, -1, 2, 0, -2, 1, 0, -1};
    constexpr float KSY[9] = {1, 2, 1, 0, 0, 0, -1, -2, -1};
    constexpr float KLP[9] = {0, 1, 0, 1, -4, 1, 0, 1, 0};

    __shared__ float xsf[8 * 484];
    __shared__ float ysf[8 * 400];
    int b = blockIdx.y;
    if (((const int*)ws)[WS_BIDX + b] != want) return;
    int tile = blockIdx.x;
    int ty = (tile >> 4) * 16, tx = (tile & 15) * 16;
    int tid = threadIdx.x;

    const float* xb = x + (size_t)b * IC * HH * WW;
    const float* wt = ws + wt_off;
    const float* bf = ws + bf_off;

    float acc[8][8];
    #pragma unroll
    for (int o = 0; o < 8; o++)
        #pragma unroll
        for (int j = 0; j < 8; j++) acc[o][j] = 0.f;

    int ocg = tid >> 5;
    int ps  = tid & 31;
    int row = ps >> 1, c0 = (ps & 1) * 8;

    for (int icc = 0; icc < 4; icc++) {
        if (icc) __syncthreads();
        for (int i = tid; i < 8 * 484; i += 256) {
            int ch = i / 484, rem = i % 484, rr = rem / 22, cc = rem % 22;
            int ic = icc * 8 + ch;
            int gy = ty - 3 + rr, gx = tx - 3 + cc;
            float v = 0.f;
            if ((unsigned)gy < HH && (unsigned)gx < WW) v = xb[(size_t)ic * HH * WW + gy * WW + gx];
            xsf[i] = v;
        }
        __syncthreads();
        for (int p = tid; p < 400; p += 256) {
            int r = p / 20, c = p % 20;
            bool inb = ((unsigned)(ty - 2 + r) < HH) && ((unsigned)(tx - 2 + c) < WW);
            #pragma unroll
            for (int ch = 0; ch < 8; ch++) {
                const float* xp = xsf + ch * 484 + r * 22 + c;
                float v = 0.f;
                #pragma unroll
                for (int k = 0; k < 9; k++) {
                    float kv = (KID == 0) ? KSX[k] : (KID == 1) ? KSY[k] : KLP[k];
                    if (kv != 0.f) v += kv * xp[(k / 3) * 22 + (k % 3)];
                }
                ysf[ch * 400 + p] = inb ? v : 0.f;
            }
        }
        __syncthreads();
        for (int ic8 = 0; ic8 < 8; ic8++) {
            const float* yc = ysf + ic8 * 400;
            const float* wbase = wt + ((icc * 8 + ic8) * 25) * 64 + ocg * 8;
            #pragma unroll
            for (int dh = 0; dh < 5; dh++) {
                #pragma unroll
                for (int dw = 0; dw < 5; dw++) {
                    const float* yp = yc + (row + dh) * 20 + c0 + dw;
                    float yv[8];
                    #pragma unroll
                    for (int j = 0; j < 8; j++) yv[j] = yp[j];
                    const float4* wp = (const float4*)(wbase + (dh * 5 + dw) * 64);
                    float4 wa = wp[0], wb = wp[1];
                    float wr[8] = {wa.x, wa.y, wa.z, wa.w, wb.x, wb.y, wb.z, wb.w};
                    #pragma unroll
                    for (int o = 0; o < 8; o++)
                        #pragma unroll
                        for (int j = 0; j < 8; j++) acc[o][j] += wr[o] * yv[j];
                }
            }
        }
    }
    float* ob = out + (size_t)b * OC * HH * WW;
    #pragma unroll
    for (int o = 0; o < 8; o++) {
        int oc = ocg * 8 + o;
        float bb = bf[oc];
        float* op = ob + (size_t)oc * HH * WW + (ty + row) * WW + tx + c0;
        if (accumulate) {
            #pragma unroll
            for (int j = 0; j < 8; j++) op[j] += scale * fmaxf(acc[o][j] + bb, 0.f);
        } else {
            #pragma unroll
            for (int j = 0; j < 8; j++) op[j] = scale * fmaxf(acc[o][j] + bb, 0.f);
        }
    }
}

// ------------------------------------------------------------------
extern "C" void kernel_launch(void* const* d_in, const int* in_sizes, int n_in,
                              void* d_out, int out_size, void* d_ws, size_t ws_size,
                              hipStream_t stream) {
    const float* x    = (const float*)d_in[0];
    const float* gw1  = (const float*)d_in[1];
    const float* gb1  = (const float*)d_in[2];
    const float* gbn  = (const float*)d_in[3];
    const float* gw2  = (const float*)d_in[4];
    const float* gb2  = (const float*)d_in[5];
    const float* mw1  = (const float*)d_in[6];
    const float* mb1  = (const float*)d_in[7];
    const float* mbn1 = (const float*)d_in[8];
    const float* mw2  = (const float*)d_in[9];
    const float* mb2  = (const float*)d_in[10];
    const float* mbn2 = (const float*)d_in[11];
    const float* sxw  = (const float*)d_in[12];
    const float* sxb  = (const float*)d_in[13];
    const float* sxbn = (const float*)d_in[14];
    const float* syw  = (const float*)d_in[15];
    const float* syb  = (const float*)d_in[16];
    const float* sybn = (const float*)d_in[17];
    const float* lw   = (const float*)d_in[18];
    const float* lb   = (const float*)d_in[19];
    const float* lbn  = (const float*)d_in[20];
    float* ws  = (float*)d_ws;
    float* out = (float*)d_out;

    prep_kernel<<<400, 256, 0, stream>>>(mw1, mb1, mbn1, mw2, mb2, mbn2,
                                         sxw, sxb, sxbn, syw, syb, sybn, lw, lb, lbn, ws);
    gap_kernel<<<256, 256, 0, stream>>>(x, ws);
    gate_kernel<<<1, 256, 0, stream>>>(gw1, gb1, gbn, gw2, gb2, ws);

    dim3 grid(256, BB);
    main_kernel<<<grid, 256, 0, stream>>>(x, ws, out);
    edge_kernel<0><<<grid, 256, 0, stream>>>(x, ws, out, 1, 0.5f, 0, WS_SXWT, WS_SXBF);
    edge_kernel<1><<<grid, 256, 0, stream>>>(x, ws, out, 1, 0.5f, 1, WS_SYWT, WS_SYBF);
    edge_kernel<2><<<grid, 256, 0, stream>>>(x, ws, out, 2, 1.0f, 0, WS_LWT, WS_LBF);
}